// Round 5
// baseline (474.536 us; speedup 1.0000x reference)
//
#include <hip/hip_runtime.h>

// Problem constants (fixed by the reference's setup_inputs)
#define NB 2          // batch
#define NN 262144     // events per batch (2^18)
#define ND 10         // temporal bins (base)
#define NR 11         // warp references (base + 1)
#define HH 256
#define WW 256
#define HWSZ 65536
#define SROWS 16      // rows per y-strip
#define NSTRIP 16     // 256 / SROWS
#define EPSF 1e-9f

// ws layout (~18.9 MB -- under the 23.07 MB proven good in R1/R2):
//   float2 recY[NB*NN]  -- (ay, dy): warped y at ref r = ay + r*dy   (streamed)
//   float4 recH[NB*NN]  -- (ax, dx, ts, pol)                         (hit path)
//   float  accum[64]    -- (sumsq, inside) per (b,r)
//
// R1/R2: 46M scattered global fp32 atomics = 2.1 ms floor -> privatize in LDS.
// R4: exclusive (b,r,strip) ownership in 64KB LDS = 466 us, but 512-thr blocks
//     capped occupancy at 34% and streamed 16B/event. R5: 1024-thr blocks
//     (2/CU -> 69% ceiling) + 8B streamed y-record.

__global__ __launch_bounds__(256) void cm_prep(
    const float* __restrict__ events,
    const float* __restrict__ flow,
    float2* __restrict__ recY,
    float4* __restrict__ recH)
{
    __shared__ float s_ev[256 * 5];
    int gid0 = blockIdx.x * 256;

    // coalesced stage of 256 events (stride-20B layout) through LDS
    const float* evb = events + (size_t)gid0 * 5;
    for (int k = threadIdx.x; k < 256 * 5; k += 256) s_ev[k] = evb[k];
    __syncthreads();

    int gid = gid0 + threadIdx.x;
    int b = gid >> 18;
    const float* e = s_ev + threadIdx.x * 5;
    float x  = e[0];
    float y  = e[1];
    float t  = e[2];
    float ts = e[3];
    float p  = e[4];

    int zi = (int)floorf(t);
    zi = zi < 0 ? 0 : (zi > ND - 1 ? ND - 1 : zi);

    int x0 = (int)floorf(x);
    x0 = x0 < 0 ? 0 : (x0 > WW - 2 ? WW - 2 : x0);
    int y0 = (int)floorf(y);
    y0 = y0 < 0 ? 0 : (y0 > HH - 2 ? HH - 2 : y0);
    float fx = fminf(fmaxf(x - (float)x0, 0.0f), 1.0f);
    float fy = fminf(fmaxf(y - (float)y0, 0.0f), 1.0f);

    const float2* f2 = (const float2*)flow + ((size_t)b * ND + zi) * HWSZ;
    float2 f00 = f2[y0 * WW + x0];
    float2 f01 = f2[y0 * WW + x0 + 1];
    float2 f10 = f2[(y0 + 1) * WW + x0];
    float2 f11 = f2[(y0 + 1) * WW + x0 + 1];
    float w00 = (1.0f - fx) * (1.0f - fy);
    float w01 = fx * (1.0f - fy);
    float w10 = (1.0f - fx) * fy;
    float w11 = fx * fy;
    float flx = w00 * f00.x + w01 * f01.x + w10 * f10.x + w11 * f11.x;
    float fly = w00 * f00.y + w01 * f01.y + w10 * f10.y + w11 * f11.y;

    recY[gid] = make_float2(fmaf(-t, fly, y), fly);
    recH[gid] = make_float4(fmaf(-t, flx, x), flx, ts, p);
}

__global__ __launch_bounds__(1024, 8) void cm_scan(
    const float4* __restrict__ recY4,   // recY viewed as pairs of events
    const float4* __restrict__ recH,
    float* __restrict__ accum)
{
    __shared__ float2 acc[2 * SROWS * WW];  // 64 KB: pol x 16 x 256 (iwe, iwt)

    int bi  = blockIdx.x;                  // 0 .. NB*NR*NSTRIP-1
    int b   = bi / (NR * NSTRIP);
    int rem = bi - b * (NR * NSTRIP);
    int r   = rem >> 4;
    int st  = rem & 15;
    int ty0  = st * SROWS;
    int tyhi = ty0 + SROWS;                // exclusive

    for (int i = threadIdx.x; i < 2 * SROWS * WW; i += 1024)
        acc[i] = make_float2(0.0f, 0.0f);
    __syncthreads();

    const float rf = (float)r;
    const int pbase = b * (NN / 2);        // pair index base

    #pragma unroll 2
    for (int it = 0; it < NN / 2048; ++it) {
        int pidx = it * 1024 + threadIdx.x;          // pair index in batch
        float4 yp = recY4[pbase + pidx];             // (ay0,dy0, ay1,dy1)

        #pragma unroll
        for (int k = 0; k < 2; ++k) {
            float ay = k ? yp.z : yp.x;
            float dy = k ? yp.w : yp.y;
            float wy = fmaf(rf, dy, ay);
            float fwy = floorf(wy);
            int yi = (int)fwy;
            if (yi + 1 < ty0 || yi >= tyhi) continue;   // 15/16+ reject

            float4 h = recH[(size_t)b * NN + 2 * pidx + k];
            float wx = fmaf(rf, h.y, h.x);
            float fwx = floorf(wx);
            int xi = (int)fwx;
            if (xi + 1 < 0 || xi >= WW) continue;

            float ax = wx - fwx;
            float ayf = wy - fwy;
            float ts = h.z;
            int pi = (int)h.w;
            pi = pi < 0 ? 0 : (pi > 1 ? 1 : pi);
            float* ap = (float*)acc + pi * (SROWS * WW * 2);

            float c00 = (1.0f - ax) * (1.0f - ayf);
            float c01 = ax * (1.0f - ayf);
            float c10 = (1.0f - ax) * ayf;
            float c11 = ax * ayf;

            #define CM_CORNER(XI, YI, WV)                                   \
                if ((XI) >= 0 && (XI) < WW && (YI) >= ty0 && (YI) < tyhi) { \
                    int li = ((YI) - ty0) * WW + (XI);                      \
                    atomicAdd(ap + 2 * li,     (WV));                       \
                    atomicAdd(ap + 2 * li + 1, (WV) * ts);                  \
                }
            CM_CORNER(xi,     yi,     c00)
            CM_CORNER(xi + 1, yi,     c01)
            CM_CORNER(xi,     yi + 1, c10)
            CM_CORNER(xi + 1, yi + 1, c11)
            #undef CM_CORNER
        }
    }
    __syncthreads();

    // fused reduction over the exclusively-owned strip (both polarities)
    float ss = 0.0f, ins = 0.0f;
    for (int i = threadIdx.x; i < SROWS * WW; i += 1024) {
        float2 c0 = acc[i];
        float2 c1 = acc[SROWS * WW + i];
        float a0 = c0.y / (c0.x + EPSF);
        float a1 = c1.y / (c1.x + EPSF);
        ss += a0 * a0 + a1 * a1;
        ins += ((c0.x + c1.x) > 0.0f) ? 1.0f : 0.0f;
    }
    #pragma unroll
    for (int off = 32; off > 0; off >>= 1) {
        ss  += __shfl_down(ss, off, 64);
        ins += __shfl_down(ins, off, 64);
    }
    __syncthreads();  // all LDS reads done before reusing acc[] for partials
    int lane = threadIdx.x & 63;
    int wv = threadIdx.x >> 6;                 // 0..15
    if (lane == 0) acc[wv] = make_float2(ss, ins);
    __syncthreads();
    if (threadIdx.x == 0) {
        float tss = 0.0f, tin = 0.0f;
        #pragma unroll
        for (int w = 0; w < 16; ++w) { tss += acc[w].x; tin += acc[w].y; }
        int br = b * NR + r;
        atomicAdd(&accum[br * 2],     tss);   // 704 total atomics -- negligible
        atomicAdd(&accum[br * 2 + 1], tin);
    }
}

__global__ void cm_final(const float* __restrict__ accum, float* __restrict__ out)
{
    int i = threadIdx.x;
    if (i < NB * NR) {
        out[i] = accum[i * 2] / (accum[i * 2 + 1] + EPSF);
    }
}

extern "C" void kernel_launch(void* const* d_in, const int* in_sizes, int n_in,
                              void* d_out, int out_size, void* d_ws, size_t ws_size,
                              hipStream_t stream) {
    const float* events = (const float*)d_in[0];
    const float* flow   = (const float*)d_in[1];

    char* ws = (char*)d_ws;
    float2* recY = (float2*)ws;
    size_t recY_bytes = (size_t)NB * NN * sizeof(float2);  // 4,194,304
    float4* recH = (float4*)(ws + recY_bytes);
    size_t recH_bytes = (size_t)NB * NN * sizeof(float4);  // 8,388,608
    float* accum = (float*)(ws + recY_bytes + recH_bytes);
    size_t accum_bytes = 256;                              // 44 floats, padded

    hipMemsetAsync(accum, 0, accum_bytes, stream);

    cm_prep<<<(NB * NN) / 256, 256, 0, stream>>>(events, flow, recY, recH);

    cm_scan<<<NB * NR * NSTRIP, 1024, 0, stream>>>((const float4*)recY, recH, accum);

    cm_final<<<1, 64, 0, stream>>>(accum, (float*)d_out);
}